// Round 1
// baseline (82.329 us; speedup 1.0000x reference)
//
#include <hip/hip_runtime.h>

// DWN pipeline, split into 4 latency-tolerant kernels with transposed
// intermediates in the workspace:
//   K1: thermometer encode -> bit-pack transposed  bitsT[3072][8] u64 (192 KB)
//   K2: layer 1 (pure 6-bit LUT)                   h1T[2000][512] f32 (4 MB)
//   K3: layer 2 (6-D multilinear)                  h2T[1000][512] f32 (2 MB)
//   K4: group-sum / tau                            out[512][10]
//
// Design: block = output column, lane = batch row. All idx/LUT-row reads are
// wave-uniform (scalar / broadcast), all intermediate reads+writes coalesced.
// No LDS, no barriers, no random byte gathers. The old fused kernel was
// 1 block/CU (2 waves/SIMD) and latency-bound on dependent gather chains.

#define FEAT  1024
#define O1    2000
#define O2    1000
#define NCLS  10

#define WS_BITS_OFF  0
#define WS_H1_OFF    (256 << 10)                 // 256 KB
#define WS_H2_OFF    ((256 << 10) + (4 << 20))   // 256 KB + 4 MB

// ---- K1: thermometer encode + transposed bit-pack -------------------------
// grid 256 blocks x 512 threads. Block b covers features [4b, 4b+4).
// Thread = batch row r. Wave w packs rows [64w, 64w+64) via __ballot.
__global__ __launch_bounds__(512) void k1_thermo_pack(
    const float* __restrict__ x,              // [512,1024]
    const float* __restrict__ thr,            // [1024,3]
    unsigned long long* __restrict__ bitsT)   // [3072][8]
{
    const int r    = threadIdx.x;
    const int w    = r >> 6;
    const int lane = r & 63;
    const int f0   = blockIdx.x * 4;

    float4 xv4 = *(const float4*)(x + (size_t)r * FEAT + f0);
    float xa[4] = {xv4.x, xv4.y, xv4.z, xv4.w};

#pragma unroll
    for (int f = 0; f < 4; ++f) {
        const float* tp = thr + (size_t)(f0 + f) * 3;  // uniform -> scalar
#pragma unroll
        for (int j = 0; j < 3; ++j) {
            unsigned long long m = __ballot(xa[f] > tp[j]);
            if (lane == 0)
                bitsT[(size_t)((f0 + f) * 3 + j) * 8 + w] = m;
        }
    }
}

// ---- K2: layer 1 — binary inputs => pure 6-bit table lookup ----------------
// grid 2000 blocks x 512 threads. Block = output o (idx1/luts1 rows uniform),
// thread = batch row r. Bit reads are wave-uniform u64 broadcasts.
__global__ __launch_bounds__(512) void k2_layer1(
    const int*   __restrict__ idx1,           // [2000,6]
    const float* __restrict__ luts1,          // [2000,64]
    const unsigned long long* __restrict__ bitsT,
    float* __restrict__ h1T)                  // [2000][512]
{
    const int o    = blockIdx.x;
    const int r    = threadIdx.x;
    const int w    = r >> 6;
    const int lane = r & 63;
    const int* ip  = idx1 + o * 6;            // uniform -> s_load

    unsigned long long m0 = bitsT[(size_t)ip[0] * 8 + w];
    unsigned long long m1 = bitsT[(size_t)ip[1] * 8 + w];
    unsigned long long m2 = bitsT[(size_t)ip[2] * 8 + w];
    unsigned long long m3 = bitsT[(size_t)ip[3] * 8 + w];
    unsigned long long m4 = bitsT[(size_t)ip[4] * 8 + w];
    unsigned long long m5 = bitsT[(size_t)ip[5] * 8 + w];

    int code = ((int)((m0 >> lane) & 1ull) << 5)
             | ((int)((m1 >> lane) & 1ull) << 4)
             | ((int)((m2 >> lane) & 1ull) << 3)
             | ((int)((m3 >> lane) & 1ull) << 2)
             | ((int)((m4 >> lane) & 1ull) << 1)
             |  (int)((m5 >> lane) & 1ull);

    h1T[(size_t)o * 512 + r] = luts1[o * 64 + code];  // gather in uniform 256B row
}

// ---- K3: layer 2 — 6-D multilinear interpolation, LSB-first fold -----------
// grid 1000 blocks x 512 threads. Block = o2 (idx2/luts2 rows uniform),
// thread = batch row r. h1T gathers are coalesced 2KB reads.
// Arithmetic kept IDENTICAL (same lerp forms, same fold order) to the
// verified fused kernel -> bitwise-equal output.
__global__ __launch_bounds__(512) void k3_layer2(
    const int*   __restrict__ idx2,           // [1000,6]
    const float* __restrict__ luts2,          // [1000,64]
    const float* __restrict__ h1T,
    float* __restrict__ h2T)                  // [1000][512]
{
    const int o   = blockIdx.x;
    const int r   = threadIdx.x;
    const int* ip = idx2 + o * 6;             // uniform -> s_load

    float xv0 = h1T[(size_t)ip[0] * 512 + r];
    float xv1 = h1T[(size_t)ip[1] * 512 + r];
    float xv2 = h1T[(size_t)ip[2] * 512 + r];
    float xv3 = h1T[(size_t)ip[3] * 512 + r];
    float xv4 = h1T[(size_t)ip[4] * 512 + r];
    float xv5 = h1T[(size_t)ip[5] * 512 + r];

    const float4* lp = (const float4*)(luts2 + (size_t)o * 64);  // uniform row
    float v[16];
#pragma unroll
    for (int q = 0; q < 16; ++q) {            // fold x5 (bit0), x4 (bit1)
        float4 e = lp[q];
        float u0 = e.x + xv5 * (e.y - e.x);
        float u1 = e.z + xv5 * (e.w - e.z);
        v[q] = u0 + xv4 * (u1 - u0);
    }
#pragma unroll
    for (int q = 0; q < 8; ++q) v[q] = v[2*q] + xv3 * (v[2*q+1] - v[2*q]);
#pragma unroll
    for (int q = 0; q < 4; ++q) v[q] = v[2*q] + xv2 * (v[2*q+1] - v[2*q]);
#pragma unroll
    for (int q = 0; q < 2; ++q) v[q] = v[2*q] + xv1 * (v[2*q+1] - v[2*q]);
    h2T[(size_t)o * 512 + r] = v[0] + xv0 * (v[1] - v[0]);
}

// ---- K4: group sum / tau, exact 10x10 two-level order ----------------------
// grid 20 blocks x 256 threads. Block = (class c, row-half), lane = row r
// -> h2T reads coalesced. Same summation order as the verified kernel.
__global__ __launch_bounds__(256) void k4_reduce(
    const float* __restrict__ h2T,
    float* __restrict__ out)                  // [512,10]
{
    const int c = blockIdx.x >> 1;
    const int r = ((blockIdx.x & 1) << 8) | threadIdx.x;
    const float* hp = h2T + (size_t)c * 100 * 512 + r;

    float s = 0.0f;
#pragma unroll
    for (int p = 0; p < 10; ++p) {
        float s2 = 0.0f;
#pragma unroll
        for (int j = 0; j < 10; ++j) s2 += hp[(size_t)(p * 10 + j) * 512];
        s += s2;
    }
    out[r * NCLS + c] = s / 3.3333333f;
}

extern "C" void kernel_launch(void* const* d_in, const int* in_sizes, int n_in,
                              void* d_out, int out_size, void* d_ws, size_t ws_size,
                              hipStream_t stream) {
    const float* x     = (const float*)d_in[0];
    const float* thr   = (const float*)d_in[1];
    const float* luts1 = (const float*)d_in[2];
    const int*   idx1  = (const int*)  d_in[3];
    const float* luts2 = (const float*)d_in[4];
    const int*   idx2  = (const int*)  d_in[5];
    float* out = (float*)d_out;

    char* ws = (char*)d_ws;
    unsigned long long* bitsT = (unsigned long long*)(ws + WS_BITS_OFF);
    float* h1T = (float*)(ws + WS_H1_OFF);
    float* h2T = (float*)(ws + WS_H2_OFF);

    k1_thermo_pack<<<FEAT / 4, 512, 0, stream>>>(x, thr, bitsT);
    k2_layer1<<<O1, 512, 0, stream>>>(idx1, luts1, bitsT, h1T);
    k3_layer2<<<O2, 512, 0, stream>>>(idx2, luts2, h1T, h2T);
    k4_reduce<<<NCLS * 2, 256, 0, stream>>>(h2T, out);
}